// Round 1
// 421.544 us; speedup vs baseline: 1.5058x; 1.5058x over previous
//
#include <hip/hip_runtime.h>
#include <math.h>

typedef _Float16 f16;
typedef _Float16 f16x8 __attribute__((ext_vector_type(8)));
typedef float f32x4 __attribute__((ext_vector_type(4)));

#define NB 16
#define SS 2048
#define DD 512

// async global->LDS, 16B per lane; LDS dst = wave-uniform base + lane*16
__device__ __forceinline__ void gl_lds16(const void* g, void* l) {
  __builtin_amdgcn_global_load_lds(
      (const __attribute__((address_space(1))) unsigned int*)g,
      (__attribute__((address_space(3))) unsigned int*)l, 16, 0, 0);
}

// ---------------- cast x (fp32) -> fp16, 8 elems/thread ----------------
__global__ __launch_bounds__(256) void cast_kernel(const float* __restrict__ x,
                                                   f16* __restrict__ o) {
  size_t i = (size_t)blockIdx.x * 256 + threadIdx.x;
  const float4* p = (const float4*)x + i * 2;
  float4 a = p[0], b = p[1];
  f16x8 v = {(f16)a.x, (f16)a.y, (f16)a.z, (f16)a.w,
             (f16)b.x, (f16)b.y, (f16)b.z, (f16)b.w};
  *((f16x8*)o + i) = v;
}

// ---------------- transpose 512x512 weight, fp32 -> fp16 ----------------
__global__ __launch_bounds__(256) void transpose_kernel(const float* __restrict__ W,
                                                        f16* __restrict__ Wt) {
  __shared__ float t[32][33];
  int bx = blockIdx.x * 32, by = blockIdx.y * 32;
  int c = threadIdx.x & 31, r0 = threadIdx.x >> 5;
  for (int r = r0; r < 32; r += 8) t[r][c] = W[(size_t)(by + r) * DD + bx + c];
  __syncthreads();
  for (int r = r0; r < 32; r += 8) Wt[(size_t)(bx + r) * DD + by + c] = (f16)t[c][r];
}

// ---------------- GEMM: C[M][N] = A[M][K=512] * Bt[N][K=512]^T ----------------
// 128x128 tile, BK=32, 4 waves (2x2 of 64x64), 16x16x32_f16 MFMA. (R2: proven)
__global__ __launch_bounds__(256) void gemm_kernel(
    const f16* __restrict__ A, long sAb, const f16* __restrict__ Bt, long sBb,
    f16* __restrict__ C, long sCb, int ldc, const float* __restrict__ bias,
    int bias_row, float scale) {
  A += (size_t)blockIdx.z * sAb;
  Bt += (size_t)blockIdx.z * sBb;
  C += (size_t)blockIdx.z * sCb;
  const int m0 = blockIdx.y * 128, n0 = blockIdx.x * 128;
  __shared__ f16 Ash[128 * 32];
  __shared__ f16 Bsh[128 * 32];
  const int tid = threadIdx.x, lane = tid & 63, wave = tid >> 6;
  const int wm = wave & 1, wn = wave >> 1;
  const int l15 = lane & 15, lq = lane >> 4;
  f32x4 acc[4][4] = {};
  const int srow = tid >> 2, part = tid & 3;
  const f16* gA = A + (size_t)(m0 + srow) * DD + part * 8;
  const f16* gB = Bt + (size_t)(n0 + srow) * DD + part * 8;
  f16* lA = &Ash[tid * 8];
  f16* lB = &Bsh[tid * 8];
  for (int kt = 0; kt < 16; ++kt) {
    gl_lds16(gA + kt * 32, lA);
    gl_lds16(gA + 64 * DD + kt * 32, lA + 2048);
    gl_lds16(gB + kt * 32, lB);
    gl_lds16(gB + 64 * DD + kt * 32, lB + 2048);
    __syncthreads();
    f16x8 af[4], bf[4];
#pragma unroll
    for (int i = 0; i < 4; ++i)
      af[i] = *(const f16x8*)&Ash[(64 * wm + 16 * i + l15) * 32 + lq * 8];
#pragma unroll
    for (int j = 0; j < 4; ++j)
      bf[j] = *(const f16x8*)&Bsh[(64 * wn + 16 * j + l15) * 32 + lq * 8];
#pragma unroll
    for (int i = 0; i < 4; ++i)
#pragma unroll
      for (int j = 0; j < 4; ++j)
        acc[i][j] = __builtin_amdgcn_mfma_f32_16x16x32_f16(af[i], bf[j], acc[i][j], 0, 0, 0);
    __syncthreads();
  }
#pragma unroll
  for (int i = 0; i < 4; ++i) {
    int rb = 64 * wm + 16 * i + lq * 4;
#pragma unroll
    for (int j = 0; j < 4; ++j) {
      int cc = n0 + 64 * wn + 16 * j + l15;
#pragma unroll
      for (int r = 0; r < 4; ++r) {
        int rr = m0 + rb + r;
        float bv = bias_row ? bias[rr] : bias[cc];
        C[(size_t)rr * ldc + cc] = (f16)((acc[i][j][r] + bv) * scale);
      }
    }
  }
}

// ---------------- flash attention, R5: single-pass over D ----------------
// Theory: R4 was LDS-pipe-bound (QK reads + softmax shuffles executed twice
// across the 2 col-passes). R5 keeps O for all 512 cols in registers
// (acco[32] = 128 VGPR; free: LDS caps us at 2 waves/SIMD and block=512
// allows 256 VGPR/wave), so QK + softmax run ONCE per key chunk:
//   - 33% fewer MFMA, ~35% fewer LDS instructions
//   - l_i via ones-column MFMA (same C-layout/rescale chain as acco)
//     -> kills the 16 sum-swizzles/iter/wave; max-reduce swizzles remain
//   - V staged by global_load_lds DMA (no reg commit). Linear 64B rows would
//     4-way conflict, so both-sides XOR swizzle: source quarter s^((e>>1)&3)
//     (lane-constant!) + same XOR on read offset -> 2-way = free
//   - defer-max (THR=8): skip 33-frag rescale when max didn't grow; P<=e^8,
//     f16 rel-precision is scale-invariant so safe
// Layouts (m89-verified 16x16x32): A[m=l15][k=lq*8+j], B[k=lq*8+j][n=l15],
// C col=l15, row=lq*4+r.
__global__ __launch_bounds__(512, 2) void attn_kernel(
    const f16* __restrict__ Q, const f16* __restrict__ K,
    const f16* __restrict__ Vt, float* __restrict__ out) {
  const int id = blockIdx.x;
  const int b = (id & 7) + ((id >> 7) << 3);  // XCD x gets batches {x, x+8}
  const int qt = (id >> 3) & 15;
  const int tid = threadIdx.x, lane = tid & 63, wave = tid >> 6;
  const int l15 = lane & 15, lq = lane >> 4;

  __shared__ __align__(16) f16 Kl[2][32][520];  // [key][d], 1040B rows: granule shifts 1/row, conflict-free
  __shared__ __align__(16) f16 Vl[2][512][32];  // [e][key], 64B rows, XOR-swizzled quarters
  __shared__ __align__(16) f16 Psh[128][40];    // per-wave-private P rows

  // persistent Q fragments: rows 128*qt + 16*wave + l15 (scale pre-folded)
  const f16* qp = Q + ((size_t)(b * SS + qt * 128 + wave * 16 + l15)) * DD + lq * 8;
  f16x8 qf[16];
#pragma unroll
  for (int kk = 0; kk < 16; ++kk) qf[kk] = *(const f16x8*)(qp + kk * 32);

  const f16* Kb = K + (size_t)b * SS * DD;   // [key][d]
  const f16* Vb = Vt + (size_t)b * DD * SS;  // [e][s]

  // V-stage lane constants: DMA lane covers (e = e0 + lane/4, phys quarter lane&3);
  // it must fetch data quarter s_data = (lane&3) ^ ((e>>1)&3) = (lane&3)^((lane>>3)&3)
  // (e0 multiple of 16 drops out). Read applies the same XOR.
  const int sdata = (lane & 3) ^ ((lane >> 3) & 3);
  const int vrow = lane >> 2;
  const int vs_off = (lq ^ ((l15 >> 1) & 3)) * 8;  // f16 offset within 32-key row

  f16x8 onef;
#pragma unroll
  for (int j = 0; j < 8; ++j) onef[j] = (f16)1.0f;

  auto stage = [&](int sb, int kb) {
#pragma unroll
    for (int rr = 0; rr < 4; ++rr) {  // K: 32 rows, 1 DMA row each
      int row = wave * 4 + rr;
      gl_lds16(Kb + ((size_t)(kb + row)) * DD + lane * 8, &Kl[sb][row][lane * 8]);
    }
#pragma unroll
    for (int i = 0; i < 4; ++i) {  // V: 512 e-rows x 32 keys, 16 rows per DMA
      int e0 = wave * 64 + i * 16;
      gl_lds16(Vb + (size_t)(e0 + vrow) * SS + kb + sdata * 8,
               (f16*)&Vl[sb][e0][0] + lane * 8);
    }
  };

  stage(0, 0);
  __syncthreads();

  f32x4 acco[32] = {};
  f32x4 accl = {};  // row-sum l via ones-MFMA, same rescale chain as acco
  float m_i[4] = {-1e30f, -1e30f, -1e30f, -1e30f};

  for (int it = 0; it < 64; ++it) {
    const int buf = it & 1;
    if (it < 63) stage(buf ^ 1, (it + 1) * 32);  // issue early, lands by barrier
    // ---- QK: S[16 rows][32 keys] ----
    f32x4 sa0 = {}, sa1 = {};
#pragma unroll
    for (int kk = 0; kk < 16; ++kk) {
      f16x8 b0 = *(const f16x8*)&Kl[buf][l15][kk * 32 + lq * 8];
      f16x8 b1 = *(const f16x8*)&Kl[buf][16 + l15][kk * 32 + lq * 8];
      sa0 = __builtin_amdgcn_mfma_f32_16x16x32_f16(qf[kk], b0, sa0, 0, 0, 0);
      sa1 = __builtin_amdgcn_mfma_f32_16x16x32_f16(qf[kk], b1, sa1, 0, 0, 0);
    }
    // ---- row max across l15 ----
    float mx[4];
#pragma unroll
    for (int r = 0; r < 4; ++r) mx[r] = fmaxf(sa0[r], sa1[r]);
#pragma unroll
    for (int d = 1; d < 16; d <<= 1)
#pragma unroll
      for (int r = 0; r < 4; ++r) mx[r] = fmaxf(mx[r], __shfl_xor(mx[r], d));
    // ---- defer-max: rescale only when max grew by > 8 ----
    bool need = false;
#pragma unroll
    for (int r = 0; r < 4; ++r) need |= (mx[r] > m_i[r] + 8.0f);
    if (__any(need)) {
      float al[4];
#pragma unroll
      for (int r = 0; r < 4; ++r) {
        float mn = fmaxf(m_i[r], mx[r]);
        al[r] = __expf(m_i[r] - mn);
        m_i[r] = mn;
      }
#pragma unroll
      for (int t = 0; t < 32; ++t)
#pragma unroll
        for (int r = 0; r < 4; ++r) acco[t][r] *= al[r];
#pragma unroll
      for (int r = 0; r < 4; ++r) accl[r] *= al[r];
    }
    // ---- P = exp(S - m), f16, via wave-private LDS reshape ----
#pragma unroll
    for (int r = 0; r < 4; ++r) {
      Psh[16 * wave + 4 * lq + r][l15] = (f16)__expf(sa0[r] - m_i[r]);
      Psh[16 * wave + 4 * lq + r][16 + l15] = (f16)__expf(sa1[r] - m_i[r]);
    }
    f16x8 pa = *(const f16x8*)&Psh[16 * wave + l15][lq * 8];
    accl = __builtin_amdgcn_mfma_f32_16x16x32_f16(pa, onef, accl, 0, 0, 0);
    // ---- PV: O[16 rows][512 cols] += P[16x32] V[32x512] ----
#pragma unroll
    for (int nn = 0; nn < 32; ++nn) {
      f16x8 vf = *(const f16x8*)&Vl[buf][nn * 16 + l15][vs_off];
      acco[nn] = __builtin_amdgcn_mfma_f32_16x16x32_f16(pa, vf, acco[nn], 0, 0, 0);
    }
    __syncthreads();  // drains DMA into buf^1; protects buf from next-iter overwrite
  }
  // ---- epilogue: O /= l, store fp32 ----
  float inv[4];
#pragma unroll
  for (int r = 0; r < 4; ++r) inv[r] = 1.0f / accl[r];
  const size_t ob = ((size_t)(b * SS + qt * 128 + wave * 16 + 4 * lq)) * DD + l15;
#pragma unroll
  for (int nn = 0; nn < 32; ++nn)
#pragma unroll
    for (int r = 0; r < 4; ++r)
      out[ob + (size_t)r * DD + nn * 16] = acco[nn][r] * inv[r];
}

extern "C" void kernel_launch(void* const* d_in, const int* in_sizes, int n_in,
                              void* d_out, int out_size, void* d_ws, size_t ws_size,
                              hipStream_t stream) {
  const float* x = (const float*)d_in[0];
  const float* Wq = (const float*)d_in[1];
  const float* bq = (const float*)d_in[2];
  const float* Wk = (const float*)d_in[3];
  const float* bk = (const float*)d_in[4];
  const float* Wv = (const float*)d_in[5];
  const float* bv = (const float*)d_in[6];
  float* out = (float*)d_out;
  f16* ws = (f16*)d_ws;
  const size_t NX = (size_t)NB * SS * DD;  // 16,777,216
  f16* xh = ws;
  f16* Qh = ws + NX;
  f16* Kh = ws + 2 * NX;
  f16* Vth = ws + 3 * NX;
  f16* WqT = ws + 4 * NX;
  f16* WkT = WqT + DD * DD;
  f16* WvT = WkT + DD * DD;

  cast_kernel<<<NX / 8 / 256, 256, 0, stream>>>(x, xh);
  dim3 tg(16, 16);
  transpose_kernel<<<tg, 256, 0, stream>>>(Wq, WqT);
  transpose_kernel<<<tg, 256, 0, stream>>>(Wk, WkT);
  transpose_kernel<<<tg, 256, 0, stream>>>(Wv, WvT);
  // Q = (x@Wq + bq) * 1/8  (scale folded, exact pow2)
  gemm_kernel<<<dim3(4, 256, 1), 256, 0, stream>>>(xh, 0, WqT, 0, Qh, 0, DD, bq, 0, 0.125f);
  // K = x@Wk + bk
  gemm_kernel<<<dim3(4, 256, 1), 256, 0, stream>>>(xh, 0, WkT, 0, Kh, 0, DD, bk, 0, 1.0f);
  // Vt[b][e][s] = WvT @ x[b]^T + bv[e]
  gemm_kernel<<<dim3(16, 4, NB), 256, 0, stream>>>(WvT, 0, xh, (long)SS * DD, Vth,
                                                   (long)DD * SS, SS, bv, 1, 1.0f);
  attn_kernel<<<256, 512, 0, stream>>>(Qh, Kh, Vth, out);
}

// Round 2
// 392.667 us; speedup vs baseline: 1.6165x; 1.0735x over previous
//
#include <hip/hip_runtime.h>
#include <math.h>

typedef _Float16 f16;
typedef _Float16 f16x2 __attribute__((ext_vector_type(2)));
typedef _Float16 f16x8 __attribute__((ext_vector_type(8)));
typedef float f32x4 __attribute__((ext_vector_type(4)));

#define NB 16
#define SS 2048
#define DD 512

// async global->LDS, 16B per lane; LDS dst = wave-uniform base + lane*16
__device__ __forceinline__ void gl_lds16(const void* g, void* l) {
  __builtin_amdgcn_global_load_lds(
      (const __attribute__((address_space(1))) unsigned int*)g,
      (__attribute__((address_space(3))) unsigned int*)l, 16, 0, 0);
}

// pack two f32 -> f16x2 word (RNE scalar converts; compiler emits cvt+pack)
__device__ __forceinline__ int pk2(float a, float b) {
  f16x2 t = {(f16)a, (f16)b};
  return __builtin_bit_cast(int, t);
}

// ---------------- cast x (fp32) -> fp16, 8 elems/thread ----------------
__global__ __launch_bounds__(256) void cast_kernel(const float* __restrict__ x,
                                                   f16* __restrict__ o) {
  size_t i = (size_t)blockIdx.x * 256 + threadIdx.x;
  const float4* p = (const float4*)x + i * 2;
  float4 a = p[0], b = p[1];
  f16x8 v = {(f16)a.x, (f16)a.y, (f16)a.z, (f16)a.w,
             (f16)b.x, (f16)b.y, (f16)b.z, (f16)b.w};
  *((f16x8*)o + i) = v;
}

// ---------------- transpose 512x512 weight, fp32 -> fp16 ----------------
__global__ __launch_bounds__(256) void transpose_kernel(const float* __restrict__ W,
                                                        f16* __restrict__ Wt) {
  __shared__ float t[32][33];
  int bx = blockIdx.x * 32, by = blockIdx.y * 32;
  int c = threadIdx.x & 31, r0 = threadIdx.x >> 5;
  for (int r = r0; r < 32; r += 8) t[r][c] = W[(size_t)(by + r) * DD + bx + c];
  __syncthreads();
  for (int r = r0; r < 32; r += 8) Wt[(size_t)(bx + r) * DD + by + c] = (f16)t[c][r];
}

// ---------------- GEMM: C[M][N] = A[M][K=512] * Bt[N][K=512]^T ----------------
// 128x128 tile, BK=32, 4 waves (2x2 of 64x64), 16x16x32_f16 MFMA. (R2: proven)
__global__ __launch_bounds__(256) void gemm_kernel(
    const f16* __restrict__ A, long sAb, const f16* __restrict__ Bt, long sBb,
    f16* __restrict__ C, long sCb, int ldc, const float* __restrict__ bias,
    int bias_row, float scale) {
  A += (size_t)blockIdx.z * sAb;
  Bt += (size_t)blockIdx.z * sBb;
  C += (size_t)blockIdx.z * sCb;
  const int m0 = blockIdx.y * 128, n0 = blockIdx.x * 128;
  __shared__ f16 Ash[128 * 32];
  __shared__ f16 Bsh[128 * 32];
  const int tid = threadIdx.x, lane = tid & 63, wave = tid >> 6;
  const int wm = wave & 1, wn = wave >> 1;
  const int l15 = lane & 15, lq = lane >> 4;
  f32x4 acc[4][4] = {};
  const int srow = tid >> 2, part = tid & 3;
  const f16* gA = A + (size_t)(m0 + srow) * DD + part * 8;
  const f16* gB = Bt + (size_t)(n0 + srow) * DD + part * 8;
  f16* lA = &Ash[tid * 8];
  f16* lB = &Bsh[tid * 8];
  for (int kt = 0; kt < 16; ++kt) {
    gl_lds16(gA + kt * 32, lA);
    gl_lds16(gA + 64 * DD + kt * 32, lA + 2048);
    gl_lds16(gB + kt * 32, lB);
    gl_lds16(gB + 64 * DD + kt * 32, lB + 2048);
    __syncthreads();
    f16x8 af[4], bf[4];
#pragma unroll
    for (int i = 0; i < 4; ++i)
      af[i] = *(const f16x8*)&Ash[(64 * wm + 16 * i + l15) * 32 + lq * 8];
#pragma unroll
    for (int j = 0; j < 4; ++j)
      bf[j] = *(const f16x8*)&Bsh[(64 * wn + 16 * j + l15) * 32 + lq * 8];
#pragma unroll
    for (int i = 0; i < 4; ++i)
#pragma unroll
      for (int j = 0; j < 4; ++j)
        acc[i][j] = __builtin_amdgcn_mfma_f32_16x16x32_f16(af[i], bf[j], acc[i][j], 0, 0, 0);
    __syncthreads();
  }
#pragma unroll
  for (int i = 0; i < 4; ++i) {
    int rb = 64 * wm + 16 * i + lq * 4;
#pragma unroll
    for (int j = 0; j < 4; ++j) {
      int cc = n0 + 64 * wn + 16 * j + l15;
#pragma unroll
      for (int r = 0; r < 4; ++r) {
        int rr = m0 + rb + r;
        float bv = bias_row ? bias[rr] : bias[cc];
        C[(size_t)rr * ldc + cc] = (f16)((acc[i][j][r] + bv) * scale);
      }
    }
  }
}

// ---------------- flash attention, R6: swapped-QK, P fully in-register ----------
// R5 post-mortem: LDS pipe saturated (8.3k cyc/iter/CU): K/V frag reads 6.1k
// (floor), P LDS round-trip ~0.5k, max-butterfly 0.7k, conflicts 1.1k (Psh).
// R6 removes everything except the floor:
//  - swapped QK: sa = mfma(Kfrag, qf) -> S^T with q=l15, keys=regs (A/B lane
//    mappings are mutual transposes, so the same registers serve; zero new loads)
//  - P stays in regs: exp -> pk2 f16 words -> 2-round butterfly (xor32 via
//    permlane [VALU], xor16 via ds_swizzle) + cndmask assembly = PV A-frag.
//    Kills 8 ds_write_b16 + 1 ds_read_b128 + their bank conflicts + 10KB LDS.
//  - defer-max with PER-LANE pre-check: common path has ZERO cross-lane
//    reduce ops; the 2-shuffle reduce + 4-bpermute al broadcast (l15-layout ->
//    4lq+r row-layout) runs only on trigger (few of 64 iters; P<=e^8 safe in f16)
//  - l via ones-MFMA (accl) unchanged; acco layout/PV/epilogue unchanged.
// Layouts (m89-verified 16x16x32): A[m=l15][k=lq*8+j], B[k=lq*8+j][n=l15],
// C col=l15, row=4lq+r.
__global__ __launch_bounds__(512, 2) void attn_kernel(
    const f16* __restrict__ Q, const f16* __restrict__ K,
    const f16* __restrict__ Vt, float* __restrict__ out) {
  const int id = blockIdx.x;
  const int b = (id & 7) + ((id >> 7) << 3);  // XCD x gets batches {x, x+8}
  const int qt = (id >> 3) & 15;
  const int tid = threadIdx.x, lane = tid & 63, wave = tid >> 6;
  const int l15 = lane & 15, lq = lane >> 4;

  __shared__ __align__(16) f16 Kl[2][32][520];  // [key][d], 1040B rows: conflict-free
  __shared__ __align__(16) f16 Vl[2][512][32];  // [e][key], XOR-swizzled quarters

  // persistent Q fragments: rows 128*qt + 16*wave + l15 (scale pre-folded)
  const f16* qp = Q + ((size_t)(b * SS + qt * 128 + wave * 16 + l15)) * DD + lq * 8;
  f16x8 qf[16];
#pragma unroll
  for (int kk = 0; kk < 16; ++kk) qf[kk] = *(const f16x8*)(qp + kk * 32);

  const f16* Kb = K + (size_t)b * SS * DD;   // [key][d]
  const f16* Vb = Vt + (size_t)b * DD * SS;  // [e][s]

  // V-stage lane constants (R5-proven): source quarter pre-swizzle + read XOR
  const int sdata = (lane & 3) ^ ((lane >> 3) & 3);
  const int vrow = lane >> 2;
  const int vs_off = (lq ^ ((l15 >> 1) & 3)) * 8;  // f16 offset within 32-key row

  f16x8 onef;
#pragma unroll
  for (int j = 0; j < 8; ++j) onef[j] = (f16)1.0f;

  auto stage = [&](int sb, int kb) {
#pragma unroll
    for (int rr = 0; rr < 4; ++rr) {  // K: 32 rows, 1 DMA row each
      int row = wave * 4 + rr;
      gl_lds16(Kb + ((size_t)(kb + row)) * DD + lane * 8, &Kl[sb][row][lane * 8]);
    }
#pragma unroll
    for (int i = 0; i < 4; ++i) {  // V: 512 e-rows x 32 keys, 16 rows per DMA
      int e0 = wave * 64 + i * 16;
      gl_lds16(Vb + (size_t)(e0 + vrow) * SS + kb + sdata * 8,
               (f16*)&Vl[sb][e0][0] + lane * 8);
    }
  };

  stage(0, 0);
  __syncthreads();

  f32x4 acco[32] = {};
  f32x4 accl = {};       // row-sum l via ones-MFMA; same rescale chain as acco
  float m = -1e30f;      // running max for q = l15 (uniform across the 4 lq lanes)

  for (int it = 0; it < 64; ++it) {
    const int buf = it & 1;
    if (it < 63) stage(buf ^ 1, (it + 1) * 32);  // issue early, lands by barrier
    // ---- QK^T (swapped): sa0 keys 4lq+r, sa1 keys 16+4lq+r, col q = l15 ----
    f32x4 sa0 = {}, sa1 = {};
#pragma unroll
    for (int kk = 0; kk < 16; ++kk) {
      f16x8 b0 = *(const f16x8*)&Kl[buf][l15][kk * 32 + lq * 8];
      f16x8 b1 = *(const f16x8*)&Kl[buf][16 + l15][kk * 32 + lq * 8];
      sa0 = __builtin_amdgcn_mfma_f32_16x16x32_f16(b0, qf[kk], sa0, 0, 0, 0);
      sa1 = __builtin_amdgcn_mfma_f32_16x16x32_f16(b1, qf[kk], sa1, 0, 0, 0);
    }
    // ---- defer-max: pure-VALU pre-check; cross-lane work only on trigger ----
    float lm = fmaxf(fmaxf(fmaxf(sa0[0], sa0[1]), fmaxf(sa0[2], sa0[3])),
                     fmaxf(fmaxf(sa1[0], sa1[1]), fmaxf(sa1[2], sa1[3])));
    if (__any(lm > m + 8.0f)) {
      float mx = lm;
      mx = fmaxf(mx, __shfl_xor(mx, 16));
      mx = fmaxf(mx, __shfl_xor(mx, 32));  // all 4 lq lanes now hold row max(q=l15)
      float mn = fmaxf(m, mx);
      float al = __expf(m - mn);
      m = mn;
      float alr[4];
#pragma unroll
      for (int r = 0; r < 4; ++r) alr[r] = __shfl(al, 4 * lq + r);  // row-layout
#pragma unroll
      for (int t = 0; t < 32; ++t)
#pragma unroll
        for (int r = 0; r < 4; ++r) acco[t][r] *= alr[r];
#pragma unroll
      for (int r = 0; r < 4; ++r) accl[r] *= alr[r];
    }
    // ---- P = exp(S - m) packed f16; source lane j(=lq) holds:
    //      A0=keys(4j,4j+1) A1=(4j+2,4j+3) B0=(16+4j,17+4j) B1=(18+4j,19+4j)
    int A0 = pk2(__expf(sa0[0] - m), __expf(sa0[1] - m));
    int A1 = pk2(__expf(sa0[2] - m), __expf(sa0[3] - m));
    int B0 = pk2(__expf(sa1[0] - m), __expf(sa1[1] - m));
    int B1 = pk2(__expf(sa1[2] - m), __expf(sa1[3] - m));
    // ---- 2-round butterfly -> pa = P[q=l15][keys 8lq..8lq+7] (A-frag) ----
    // R1 (xor32): low lq send B, high send A.  X: lq0=A(j2) lq1=A(j3) lq2=B(j0) lq3=B(j1)
    const bool low = (lq < 2);
    int s0 = low ? B0 : A0, s1 = low ? B1 : A1;
    int X0 = __shfl_xor(s0, 32), X1 = __shfl_xor(s1, 32);
    int Y0 = low ? A0 : B0, Y1 = low ? A1 : B1;  // own kept pair
    // R2 (xor16): lq0,lq3 send X; lq1,lq2 send Y.  Z: lq0=A(j1) lq1=A(j2) lq2=B(j1) lq3=B(j2)
    const bool sx = (lq == 0) || (lq == 3);
    int t0 = sx ? X0 : Y0, t1 = sx ? X1 : Y1;
    int Z0 = __shfl_xor(t0, 16), Z1 = __shfl_xor(t1, 16);
    // assemble: pair1 = lq0:Y lq1:Z lq2:X lq3:Z ; pair2 = lq0:Z lq1:X lq2:Z lq3:Y
    union PU { int i[4]; f16x8 v; } pu;
    pu.i[0] = (lq == 0) ? Y0 : ((lq == 2) ? X0 : Z0);
    pu.i[1] = (lq == 0) ? Y1 : ((lq == 2) ? X1 : Z1);
    pu.i[2] = (lq == 1) ? X0 : ((lq == 3) ? Y0 : Z0);
    pu.i[3] = (lq == 1) ? X1 : ((lq == 3) ? Y1 : Z1);
    f16x8 pa = pu.v;
    accl = __builtin_amdgcn_mfma_f32_16x16x32_f16(pa, onef, accl, 0, 0, 0);
    // ---- PV: O[16 rows][512 cols] += P[16x32] V[32x512] ----
#pragma unroll
    for (int nn = 0; nn < 32; ++nn) {
      f16x8 vf = *(const f16x8*)&Vl[buf][nn * 16 + l15][vs_off];
      acco[nn] = __builtin_amdgcn_mfma_f32_16x16x32_f16(pa, vf, acco[nn], 0, 0, 0);
    }
    __syncthreads();  // drains DMA into buf^1; protects buf from next-iter overwrite
  }
  // ---- epilogue: O /= l, store fp32 ----
  float inv[4];
#pragma unroll
  for (int r = 0; r < 4; ++r) inv[r] = 1.0f / accl[r];
  const size_t ob = ((size_t)(b * SS + qt * 128 + wave * 16 + 4 * lq)) * DD + l15;
#pragma unroll
  for (int nn = 0; nn < 32; ++nn)
#pragma unroll
    for (int r = 0; r < 4; ++r)
      out[ob + (size_t)r * DD + nn * 16] = acco[nn][r] * inv[r];
}

extern "C" void kernel_launch(void* const* d_in, const int* in_sizes, int n_in,
                              void* d_out, int out_size, void* d_ws, size_t ws_size,
                              hipStream_t stream) {
  const float* x = (const float*)d_in[0];
  const float* Wq = (const float*)d_in[1];
  const float* bq = (const float*)d_in[2];
  const float* Wk = (const float*)d_in[3];
  const float* bk = (const float*)d_in[4];
  const float* Wv = (const float*)d_in[5];
  const float* bv = (const float*)d_in[6];
  float* out = (float*)d_out;
  f16* ws = (f16*)d_ws;
  const size_t NX = (size_t)NB * SS * DD;  // 16,777,216
  f16* xh = ws;
  f16* Qh = ws + NX;
  f16* Kh = ws + 2 * NX;
  f16* Vth = ws + 3 * NX;
  f16* WqT = ws + 4 * NX;
  f16* WkT = WqT + DD * DD;
  f16* WvT = WkT + DD * DD;

  cast_kernel<<<NX / 8 / 256, 256, 0, stream>>>(x, xh);
  dim3 tg(16, 16);
  transpose_kernel<<<tg, 256, 0, stream>>>(Wq, WqT);
  transpose_kernel<<<tg, 256, 0, stream>>>(Wk, WkT);
  transpose_kernel<<<tg, 256, 0, stream>>>(Wv, WvT);
  // Q = (x@Wq + bq) * 1/8  (scale folded, exact pow2)
  gemm_kernel<<<dim3(4, 256, 1), 256, 0, stream>>>(xh, 0, WqT, 0, Qh, 0, DD, bq, 0, 0.125f);
  // K = x@Wk + bk
  gemm_kernel<<<dim3(4, 256, 1), 256, 0, stream>>>(xh, 0, WkT, 0, Kh, 0, DD, bk, 0, 1.0f);
  // Vt[b][e][s] = WvT @ x[b]^T + bv[e]
  gemm_kernel<<<dim3(16, 4, NB), 256, 0, stream>>>(WvT, 0, xh, (long)SS * DD, Vth,
                                                   (long)DD * SS, SS, bv, 1, 1.0f);
  attn_kernel<<<256, 512, 0, stream>>>(Qh, Kh, Vth, out);
}